// Round 7
// baseline (1538.533 us; speedup 1.0000x reference)
//
#include <hip/hip_runtime.h>
#include <hip/hip_bf16.h>

// DSSResNet on MI355X.
//  enc(fp32) -> 3x { conv(MFMA bf16, reg-A, fused transpose-out) x2 } -> 4x { chunked-SSM DSS -> MFMA GLU+LN } -> dec(MFMA)
// DSS chunking (C=128): y[i] = T@x (intra) + Re(r^{i+1} Sf) + Re(r^{127-i} Sb); S via 64-step chunk scan.
// Precision: A*x = Ah*xh + Ah*xl + Al*xh (hi/lo bf16 compensation); P fp32; S hi/lo bf16.
// A-operands (weights, T/V matrices) are stored per-FRAGMENT-linear and loaded to VGPRs
// (global_load_dwordx4, depth-2 pipeline) -> K-loops run barrier-free.

#define BN   16
#define HCH  128
#define LSEQ 8192
#define NST  32
#define NLAY 4
#define XT_BSTRIDE 2101248ull   // 8208 rows (l=-8..8199) * 256 B per b

typedef __attribute__((ext_vector_type(4))) float f32x4;
typedef __attribute__((ext_vector_type(8))) short short8;
typedef unsigned short u16;
typedef unsigned int   u32;

struct __align__(8) U2 { u32 x, y; };
struct __align__(16) US8 { u16 v[8]; };
struct __align__(8) US4 { u16 v[4]; };

__device__ __forceinline__ u16 f2bf(float f){
  union { float f; u32 u; } v; v.f = f;
  u32 u = v.u;
  return (u16)((u + 0x7fffu + ((u >> 16) & 1u)) >> 16);   // RNE
}
__device__ __forceinline__ float bf2f(u32 lo16){
  union { u32 u; float f; } v; v.u = lo16 << 16; return v.f;
}
__device__ __forceinline__ float geluf(float v){
  return 0.5f * v * (1.0f + erff(v * 0.70710678118654752f));
}

#define GLDS16(g, l) \
  __builtin_amdgcn_global_load_lds((const __attribute__((address_space(1))) u32*)(g), \
                                   (__attribute__((address_space(3))) u32*)(l), 16, 0, 0)

// load 8 A-fragments (2 ks x 4 mt) from per-fragment-linear global layout into regs
#define LOAD_FRAGS(F, BASE) do { \
  _Pragma("unroll") for (int _ks = 0; _ks < 2; ++_ks) \
    _Pragma("unroll") for (int _mt = 0; _mt < 4; ++_mt) \
      F[_ks * 4 + _mt] = *(const short8*)((BASE) + _ks * 4096 + _mt * 1024); \
} while (0)

// one K=64 MFMA pass: A from regs F, B from LDS tile BT (row stride STRIDE bytes, k base KB0)
#define MFMA_PASS(F, BT, KB0, STRIDE) do { \
  _Pragma("unroll") for (int _ks = 0; _ks < 2; ++_ks){ \
    int _kb = (KB0) + _ks * 32 + lhi * 8; \
    short8 _bf[4]; \
    _Pragma("unroll") for (int _nt = 0; _nt < 4; ++_nt){ \
      int _col = wc * 64 + _nt * 16 + lan15; \
      _bf[_nt] = *(const short8*)((BT) + _col * (STRIDE) + (((_kb) * 2) ^ ((_col & 7) << 4))); \
    } \
    _Pragma("unroll") for (int _mt = 0; _mt < 4; ++_mt) \
      _Pragma("unroll") for (int _nt = 0; _nt < 4; ++_nt) \
        acc[_mt][_nt] = __builtin_amdgcn_mfma_f32_16x16x32_bf16(F[_ks * 4 + _mt], _bf[_nt], acc[_mt][_nt], 0, 0, 0); \
  } \
} while (0)

// ---------------- zero xTs halo rows (l=-8..-1, 8192..8199) ----------------
__global__ void k_xpad(u16* xTs){
  int b = blockIdx.x, t = threadIdx.x;
  char* base = (char*)xTs + (size_t)b * XT_BSTRIDE;
  int r = t >> 4;
  int row = (r < 8) ? r : (8192 + r);
  f32x4 z = {0.f, 0.f, 0.f, 0.f};
  *(f32x4*)(base + (size_t)row * 256 + (size_t)(t & 15) * 16) = z;
}

// ---------------- resnet weights -> bf16 per-fragment layout ----------------
// byte = idx*2, idx = ((((((conv*14+c)*2+wr)*2+ks)*4+mt)*64+lane)*8+e)
__global__ void k_wxform(const float* __restrict__ w1, const float* __restrict__ w2, u16* __restrict__ wfr){
  int idx = blockIdx.x * 256 + threadIdx.x;
  if (idx >= 6 * 114688) return;
  int e = idx & 7, r = idx >> 3;
  int lane = r & 63; r >>= 6;
  int mt = r & 3; r >>= 2;
  int ks = r & 1; r >>= 1;
  int wr = r & 1; r >>= 1;
  int c = r % 14; int conv = r / 14;
  int co = wr * 64 + mt * 16 + (lane & 15);
  int K = c * 64 + ks * 32 + (lane >> 4) * 8 + e;
  int k = K >> 7, ci = K & 127;
  const float* src = (conv & 1) ? w2 : w1;
  int blk = conv >> 1;
  float v = src[(((size_t)blk * 128 + co) * 128 + ci) * 7 + k];
  wfr[idx] = f2bf(v);
}

// ---------------- decoder weights -> bf16 [16co][1920K] swizzled ----------------
__global__ void k_wdec(const float* __restrict__ dw, u16* __restrict__ wd){
  int idx = blockIdx.x * 256 + threadIdx.x;
  if (idx >= 16 * 1920) return;
  int co = idx / 1920, K = idx % 1920;
  int k = K >> 7, ci = K & 127;
  float v = (co < 5) ? dw[((size_t)co * 128 + ci) * 15 + k] : 0.f;
  size_t byteoff = (size_t)co * 3840 + (u32)((K * 2) ^ ((co & 7) << 4));
  *(u16*)((char*)wd + byteoff) = f2bf(v);
}

// ---------------- GLU weights -> per-fragment layout ----------------
// byte = idx*2, idx = ((((((layer*4+a)*4+wv)*2+ks)*4+mt)*64+lane)*8+e)
// a: 0=hi(k0:64) 1=hi(k64:128) 2=lo(k0:64) 3=lo(k64:128); q rows interleaved (even=a-row, odd=g-row)
// per layer: 4*16384 u16 = 131072 B
__global__ void k_wglu(const float* __restrict__ ow, u16* __restrict__ wg){
  int idx = blockIdx.x * 256 + threadIdx.x;
  if (idx >= NLAY * 65536) return;
  int e = idx & 7, r = idx >> 3;
  int lane = r & 63; r >>= 6;
  int mt = r & 3; r >>= 2;
  int ks = r & 1; r >>= 1;
  int wv = r & 3; r >>= 2;
  int a = r & 3; int layer = r >> 2;
  int q = wv * 64 + mt * 16 + (lane & 15);
  int k = (a & 1) * 64 + ks * 32 + (lane >> 4) * 8 + e;
  int row = (q & 1) ? (128 + (q >> 1)) : (q >> 1);
  float v = ow[((size_t)layer * 256 + row) * 128 + k];
  u16 hb = f2bf(v);
  wg[idx] = (a < 2) ? hb : f2bf(v - bf2f(hb));
}

// ---------------- DSS per-layer params ----------------
__global__ void k_dssprep(const float* __restrict__ lam_re, const float* __restrict__ lam_im,
                          const float* __restrict__ log_dt, const float* __restrict__ W_re,
                          const float* __restrict__ W_im, float* __restrict__ dssp){
  int idx = blockIdx.x * 256 + threadIdx.x;
  if (idx >= NLAY * HCH * NST) return;
  int layer = idx / (HCH * NST);
  int hn = idx % (HCH * NST);
  int h = hn / NST, n = hn % NST;
  float Lre = -expf(lam_re[layer * NST + n]);
  float Lim = lam_im[layer * NST + n];
  float dt  = expf(log_dt[layer * HCH + h]);
  float are = dt * Lre, aim = dt * Lim;
  float er = expf(are);
  float rre = er * cosf(aim);
  float rim = er * sinf(aim);
  float nre = rre - 1.f, nim = rim;
  float den = 1.f / (Lre * Lre + Lim * Lim);
  float fre = (nre * Lre + nim * Lim) * den;
  float fim = (nim * Lre - nre * Lim) * den;
  float* base = dssp + (size_t)layer * 6 * HCH * NST;
  base[(0 * HCH + h) * NST + n] = rre;
  base[(1 * HCH + h) * NST + n] = rim;
  #pragma unroll
  for (int cc = 0; cc < 2; ++cc){
    float wr_ = W_re[(((size_t)layer * 2 + cc) * HCH + h) * NST + n];
    float wi_ = W_im[(((size_t)layer * 2 + cc) * HCH + h) * NST + n];
    base[((2 + 2 * cc) * HCH + h) * NST + n] = wr_ * fre - wi_ * fim;
    base[((3 + 2 * cc) * HCH + h) * NST + n] = wr_ * fim + wi_ * fre;
  }
}

// ---------------- per-layer chunk matrices (hi/lo bf16, per-fragment layout) ----------------
// A1c per h (65536 B): idx = (((((g*2+wr)*2+ks)*4+mt)*64+lane)*8+e); g: 0=Ah(k0) 1=Ah(k64) 2=Al(k0) 3=Al(k64)
// A2c per h (131072 B): idx = (((((a*2+wr)*2+ks)*4+mt)*64+lane)*8+e); a: 0-3 T slices, 4=Vfh 5=Vfl 6=Vbh 7=Vbl
__global__ __launch_bounds__(256) void k_mats(const float* __restrict__ pp,
                                              u16* __restrict__ A1c, u16* __restrict__ A2c,
                                              float* __restrict__ rC){
  int h = blockIdx.x, t = threadIdx.x;
  __shared__ float pre[129][33], pim[129][33];
  __shared__ float w0re[32], w0im[32], w1re[32], w1im[32];
  __shared__ float tf[128], tb[128];
  if (t < 32){
    int n = t;
    float rre = pp[(0 * HCH + h) * NST + n], rim = pp[(1 * HCH + h) * NST + n];
    w0re[n] = pp[(2 * HCH + h) * NST + n]; w0im[n] = pp[(3 * HCH + h) * NST + n];
    w1re[n] = pp[(4 * HCH + h) * NST + n]; w1im[n] = pp[(5 * HCH + h) * NST + n];
    float pr = 1.f, pi = 0.f;
    pre[0][n] = 1.f; pim[0][n] = 0.f;
    for (int p = 1; p <= 128; ++p){
      float nr = pr * rre - pi * rim;
      float ni = pr * rim + pi * rre;
      pr = nr; pi = ni;
      pre[p][n] = pr; pim[p][n] = pi;
    }
    rC[h * 64 + 2 * n] = pr; rC[h * 64 + 2 * n + 1] = pi;
  }
  __syncthreads();
  if (t < 128){
    float s = 0.f;
    for (int n = 0; n < 32; ++n) s += w0re[n] * pre[t][n] - w0im[n] * pim[t][n];
    tf[t] = s;
  } else {
    int d = t - 128;
    if (d == 0) tb[0] = 0.f;
    else {
      float s = 0.f;
      for (int n = 0; n < 32; ++n) s += w1re[n] * pre[d - 1][n] - w1im[n] * pim[d - 1][n];
      tb[d] = s;
    }
  }
  __syncthreads();
  for (int idx = t; idx < 32768; idx += 256){
    int e = idx & 7, r = idx >> 3;
    int lane = r & 63; r >>= 6;
    int mt = r & 3; r >>= 2;
    int ks = r & 1; r >>= 1;
    int wr = r & 1; r >>= 1;
    int g = r;
    int q = wr * 64 + mt * 16 + (lane & 15);
    int j = (g & 1) * 64 + ks * 32 + (lane >> 4) * 8 + e;
    int n, p; float wr_, wi_;
    if (q < 64){ n = q >> 1; p = 127 - j; wr_ = w0re[n]; wi_ = w0im[n]; }
    else       { n = (q - 64) >> 1; p = j; wr_ = w1re[n]; wi_ = w1im[n]; }
    float pr = pre[p][n], pi = pim[p][n];
    float v = (q & 1) ? (wr_ * pi + wi_ * pr) : (wr_ * pr - wi_ * pi);
    u16 hb = f2bf(v);
    u16 ob = (g < 2) ? hb : f2bf(v - bf2f(hb));
    *(u16*)((char*)A1c + (size_t)h * 65536 + (size_t)idx * 2) = ob;
  }
  for (int idx = t; idx < 65536; idx += 256){
    int e = idx & 7, r = idx >> 3;
    int lane = r & 63; r >>= 6;
    int mt = r & 3; r >>= 2;
    int ks = r & 1; r >>= 1;
    int wr = r & 1; r >>= 1;
    int a = r;
    int i = wr * 64 + mt * 16 + (lane & 15);
    int ka = ks * 32 + (lane >> 4) * 8 + e;
    float v; bool lo;
    if (a < 4){
      int j = (a & 1) * 64 + ka;
      v = (i >= j) ? tf[i - j] : tb[j - i];
      lo = (a >= 2);
    } else {
      int n = ka >> 1;
      int p = (a < 6) ? (i + 1) : (127 - i);
      v = (ka & 1) ? -pim[p][n] : pre[p][n];
      lo = (a == 5) || (a == 7);
    }
    u16 hb = f2bf(v);
    u16 ob = lo ? f2bf(v - bf2f(hb)) : hb;
    *(u16*)((char*)A2c + (size_t)h * 131072 + (size_t)idx * 2) = ob;
  }
}

// ---------------- encoder conv: (B,5,L) -> (B,128,L), K=15 'same', fp32 ----------------
__global__ __launch_bounds__(128) void k_enc(const float* __restrict__ xin, const float* __restrict__ w,
                                             const float* __restrict__ bias, float* __restrict__ X){
  int b = blockIdx.y, l0 = blockIdx.x * 64;
  int t = threadIdx.x;
  __shared__ float xs[5][78];
  for (int i = t; i < 5 * 78; i += 128){
    int ci = i / 78, j = i % 78;
    int l = l0 - 7 + j;
    xs[ci][j] = (l >= 0 && l < LSEQ) ? xin[((size_t)b * 5 + ci) * LSEQ + l] : 0.f;
  }
  float wreg[75];
  #pragma unroll
  for (int i = 0; i < 75; ++i) wreg[i] = w[t * 75 + i];
  float bc = bias[t];
  __syncthreads();
  size_t orow = ((size_t)b * HCH + t) * LSEQ + l0;
  for (int gb = 0; gb < 8; ++gb){
    float acc[8] = {0, 0, 0, 0, 0, 0, 0, 0};
    #pragma unroll
    for (int ci = 0; ci < 5; ++ci){
      #pragma unroll
      for (int k = 0; k < 15; ++k){
        float wv = wreg[ci * 15 + k];
        #pragma unroll
        for (int j = 0; j < 8; ++j)
          acc[j] = fmaf(wv, xs[ci][gb * 8 + j + k], acc[j]);
      }
    }
    f32x4 o0 = {acc[0] + bc, acc[1] + bc, acc[2] + bc, acc[3] + bc};
    f32x4 o1 = {acc[4] + bc, acc[5] + bc, acc[6] + bc, acc[7] + bc};
    *(f32x4*)&X[orow + gb * 8]     = o0;
    *(f32x4*)&X[orow + gb * 8 + 4] = o1;
  }
}

// ---------------- X (b,h,l) fp32 -> xTs (b,l,ci) bf16, row-swizzled by (l&7) ----------------
__global__ __launch_bounds__(256) void k_xform(const float* __restrict__ Xin, u16* __restrict__ xTs){
  int b = blockIdx.y, l0 = blockIdx.x * 64;
  int t = threadIdx.x;
  __shared__ float tile[128][65];
  #pragma unroll
  for (int it = 0; it < 32; ++it){
    int idx = t + it * 256;
    int ci = idx >> 6, j = idx & 63;
    tile[ci][j] = Xin[((size_t)b * HCH + ci) * LSEQ + l0 + j];
  }
  __syncthreads();
  int rl = t >> 2, q = t & 3;
  int l = l0 + rl;
  char* rowp = (char*)xTs + (size_t)b * XT_BSTRIDE + (size_t)(l + 8) * 256;
  u32 key = ((u32)l & 7u) << 4;
  #pragma unroll
  for (int ii = 0; ii < 8; ++ii){
    int c0 = q * 32 + ii * 4;
    U2 val;
    val.x = (u32)f2bf(tile[c0 + 0][rl]) | ((u32)f2bf(tile[c0 + 1][rl]) << 16);
    val.y = (u32)f2bf(tile[c0 + 2][rl]) | ((u32)f2bf(tile[c0 + 3][rl]) << 16);
    *(U2*)(rowp + (((u32)(c0 * 2)) ^ key)) = val;
  }
}

// ---------------- resnet conv (K=7) as MFMA GEMM, reg-A, barrier-free K-loop ----------------
__global__ __launch_bounds__(256) void k_conv(
    const u16* __restrict__ xTs, const u16* __restrict__ wfr,
    const float* __restrict__ bng, const float* __restrict__ bnb, const float* __restrict__ bnbe,
    const float* __restrict__ Xres, float* __restrict__ Xout, u16* __restrict__ xTsOut)
{
  int b = blockIdx.y, l0 = blockIdx.x * 128;
  int tid = threadIdx.x, lane = tid & 63, wv = tid >> 6;
  int wr = wv >> 1, wc = wv & 1;
  int lan15 = lane & 15, lhi = lane >> 4;

  __shared__ alignas(16) u16 xt[144 * 128];   // 36864 B

  const char* xsrc = (const char*)xTs + (size_t)b * XT_BSTRIDE + (size_t)l0 * 256;
  #pragma unroll
  for (int is = 0; is < 9; ++is){
    int off = is * 4096 + wv * 1024;
    GLDS16(xsrc + off + (lane << 4), (char*)xt + off);
  }
  const char* wb = (const char*)wfr + (size_t)wr * 8192 + ((u32)lane << 4);
  short8 afA[8], afB[8];
  LOAD_FRAGS(afA, wb);
  LOAD_FRAGS(afB, wb + 16384);
  asm volatile("s_waitcnt vmcnt(0)" ::: "memory");
  __syncthreads();

  f32x4 acc[4][4];
  #pragma unroll
  for (int i = 0; i < 4; ++i)
    #pragma unroll
    for (int j = 0; j < 4; ++j) acc[i][j] = (f32x4){0.f, 0.f, 0.f, 0.f};

  for (int c = 0; c < 14; c += 2){
    int k = c >> 1;
    #pragma unroll
    for (int ks = 0; ks < 2; ++ks){
      int ci0 = ks * 32 + lhi * 8;
      short8 bf[4];
      #pragma unroll
      for (int nt = 0; nt < 4; ++nt){
        int ll = wc * 64 + nt * 16 + lan15;
        int row = ll + k + 5;
        int lg = l0 + ll + k - 3;
        bf[nt] = *(const short8*)((const char*)xt + row * 256 + ((ci0 * 2) ^ ((lg & 7) << 4)));
      }
      #pragma unroll
      for (int mt = 0; mt < 4; ++mt)
        #pragma unroll
        for (int nt = 0; nt < 4; ++nt)
          acc[mt][nt] = __builtin_amdgcn_mfma_f32_16x16x32_bf16(afA[ks * 4 + mt], bf[nt], acc[mt][nt], 0, 0, 0);
    }
    if (c + 2 < 14) LOAD_FRAGS(afA, wb + (size_t)(c + 2) * 16384);
    #pragma unroll
    for (int ks = 0; ks < 2; ++ks){
      int ci0 = 64 + ks * 32 + lhi * 8;
      short8 bf[4];
      #pragma unroll
      for (int nt = 0; nt < 4; ++nt){
        int ll = wc * 64 + nt * 16 + lan15;
        int row = ll + k + 5;
        int lg = l0 + ll + k - 3;
        bf[nt] = *(const short8*)((const char*)xt + row * 256 + ((ci0 * 2) ^ ((lg & 7) << 4)));
      }
      #pragma unroll
      for (int mt = 0; mt < 4; ++mt)
        #pragma unroll
        for (int nt = 0; nt < 4; ++nt)
          acc[mt][nt] = __builtin_amdgcn_mfma_f32_16x16x32_bf16(afB[ks * 4 + mt], bf[nt], acc[mt][nt], 0, 0, 0);
    }
    if (c + 3 < 14) LOAD_FRAGS(afB, wb + (size_t)(c + 3) * 16384);
  }

  __syncthreads();   // all waves done reading xt; reuse as transpose buffer
  bool hasres = (Xres != nullptr);
  bool hasout = (Xout != nullptr);
  u16* tr = xt;
  #pragma unroll
  for (int mt = 0; mt < 4; ++mt){
    float A4[4], B4[4];
    int co0 = wr * 64 + mt * 16 + (lhi << 2);
    #pragma unroll
    for (int reg = 0; reg < 4; ++reg){
      A4[reg] = bng[co0 + reg] * 0.99999500003749968f;
      B4[reg] = fmaf(bnb[co0 + reg], A4[reg], bnbe[co0 + reg]);
    }
    #pragma unroll
    for (int nt = 0; nt < 4; ++nt){
      int ll = wc * 64 + nt * 16 + lan15;
      int l = l0 + ll;
      US4 o;
      #pragma unroll
      for (int reg = 0; reg < 4; ++reg){
        float v = fmaf(acc[mt][nt][reg], A4[reg], B4[reg]);
        if (hasres) v += Xres[((size_t)b * HCH + co0 + reg) * LSEQ + l];
        v = fmaxf(v, 0.f);
        if (hasout) Xout[((size_t)b * HCH + co0 + reg) * LSEQ + l] = v;
        o.v[reg] = f2bf(v);
      }
      *(US4*)((char*)tr + ll * 256 + (u32)((co0 * 2) ^ ((ll & 7) << 4))) = o;
    }
  }
  if (xTsOut){
    __syncthreads();
    int row = tid >> 1, half = tid & 1;
    const char* s = (const char*)tr + row * 256 + half * 128;
    char* d = (char*)xTsOut + (size_t)b * XT_BSTRIDE + (size_t)(l0 + row + 8) * 256 + half * 128;
    #pragma unroll
    for (int i = 0; i < 8; ++i)
      *(f32x4*)(d + i * 16) = *(const f32x4*)(s + i * 16);
  }
}

// ---------------- stage x tile (hi/lo bf16) into LDS: [128 col][128 k], col=(c&7)*16+b ----------------
__device__ __forceinline__ void stage_x_tile(const float* __restrict__ X, int h, int ct,
                                             char* xh, char* xl, int t){
  int k8 = t & 15;
  int c0 = t >> 4;
  #pragma unroll
  for (int it = 0; it < 8; ++it){
    int col = c0 + it * 16;
    int c = ct * 8 + (col >> 4), b = col & 15;
    const float* src = X + ((size_t)b * HCH + h) * LSEQ + (size_t)c * 128 + k8 * 8;
    f32x4 v0 = *(const f32x4*)src;
    f32x4 v1 = *(const f32x4*)(src + 4);
    US8 hi, lo;
    #pragma unroll
    for (int e = 0; e < 4; ++e){
      u16 hb = f2bf(v0[e]);
      hi.v[e] = hb; lo.v[e] = f2bf(v0[e] - bf2f(hb));
      u16 hb2 = f2bf(v1[e]);
      hi.v[e + 4] = hb2; lo.v[e + 4] = f2bf(v1[e] - bf2f(hb2));
    }
    u32 off = (u32)col * 256 + (u32)((k8 * 16) ^ ((col & 7) << 4));
    *(US8*)(xh + off) = hi;
    *(US8*)(xl + off) = lo;
  }
}

// ---------------- GEMM1: P = A1h@xh + A1h@xl + A1l@xh; reg-A, 1 barrier ----------------
__global__ __launch_bounds__(256) void k_dss1(const float* __restrict__ X,
                                              const u16* __restrict__ A1c,
                                              float* __restrict__ P){
  int h = blockIdx.x, ct = blockIdx.y;
  int tid = threadIdx.x, lane = tid & 63, wv = tid >> 6;
  int wr = wv >> 1, wc = wv & 1, lan15 = lane & 15, lhi = lane >> 4;
  __shared__ alignas(16) u16 bx[32768];      // xh [0,32KB) xl [32KB,64KB)

  stage_x_tile(X, h, ct, (char*)bx, (char*)bx + 32768, tid);
  const char* wb = (const char*)A1c + (size_t)h * 65536 + (size_t)wr * 8192 + ((u32)lane << 4);
  short8 fA[8], fB[8];
  LOAD_FRAGS(fA, wb);
  LOAD_FRAGS(fB, wb + 16384);
  __syncthreads();

  f32x4 acc[4][4];
  #pragma unroll
  for (int i = 0; i < 4; ++i)
    #pragma unroll
    for (int j = 0; j < 4; ++j) acc[i][j] = (f32x4){0.f, 0.f, 0.f, 0.f};

  const char* xh = (const char*)bx;
  const char* xl = (const char*)bx + 32768;
  MFMA_PASS(fA, xh, 0, 256);
  MFMA_PASS(fA, xl, 0, 256);
  LOAD_FRAGS(fA, wb + 2 * 16384);
  MFMA_PASS(fB, xh, 64, 256);
  MFMA_PASS(fB, xl, 64, 256);
  LOAD_FRAGS(fB, wb + 3 * 16384);
  MFMA_PASS(fA, xh, 0, 256);
  MFMA_PASS(fB, xh, 64, 256);

  #pragma unroll
  for (int mt = 0; mt < 4; ++mt)
    #pragma unroll
    for (int nt = 0; nt < 4; ++nt){
      int col = ct * 128 + wc * 64 + nt * 16 + lan15;
      int q0 = wr * 64 + mt * 16 + (lhi << 2);
      *(f32x4*)&P[((size_t)h * 1024 + col) * 128 + q0] = acc[mt][nt];
    }
}

// ---------------- chunk scan (fp32): S[c] written (hi/lo bf16, swizzled) before update ----------------
__global__ __launch_bounds__(256) void k_scan(const float* __restrict__ P,
                                              const float* __restrict__ rC,
                                              u16* __restrict__ Sf, u16* __restrict__ Sb){
  int part = blockIdx.x & 3, h = blockIdx.x >> 2;
  int t = threadIdx.x;
  int dir = part >> 1;
  int b = (part & 1) * 8 + (t >> 5);
  int n = t & 31;
  float rre = rC[h * 64 + 2 * n], rim = rC[h * 64 + 2 * n + 1];
  u16* SO = dir ? Sb : Sf;
  const float* pbase = P + (size_t)h * 131072 + (size_t)b * 128 + dir * 64 + 2 * n;
  float sre = 0.f, sim = 0.f;
  u32 key = ((u32)b & 7u) << 4;
  for (int ii = 0; ii < 64; ++ii){
    int c = dir ? (63 - ii) : ii;
    u16 hr = f2bf(sre), hm = f2bf(sim);
    u32 hw = (u32)hr | ((u32)hm << 16);
    u32 lw = (u32)f2bf(sre - bf2f(hr)) | ((u32)f2bf(sim - bf2f(hm)) << 16);
    char* sp = (char*)SO + ((size_t)(h * 8 + (c >> 3)) * 2) * 16384
             + (size_t)((c & 7) * 16 + b) * 128 + (u32)((4 * n) ^ key);
    *(u32*)sp = hw;
    *(u32*)(sp + 16384) = lw;
    const float* pp = pbase + (size_t)c * 2048;
    float pr = pp[0], pi = pp[1];
    float nr = rre * sre - rim * sim + pr;
    float ni = rre * sim + rim * sre + pi;
    sre = nr; sim = ni;
  }
}

// ---------------- GEMM2: Y = Vf@Sf + Vb@Sb + T@x; reg-A, 3 barriers; G = gelu(Y + D*x) ----------------
__global__ __launch_bounds__(256) void k_dss2(const float* __restrict__ X,
                                              const u16* __restrict__ A2c,
                                              const u16* __restrict__ Sf,
                                              const u16* __restrict__ Sb,
                                              const float* __restrict__ Dv,
                                              float* __restrict__ G){
  int h = blockIdx.x, ct = blockIdx.y;
  int tid = threadIdx.x, lane = tid & 63, wv = tid >> 6;
  int wr = wv >> 1, wc = wv & 1, lan15 = lane & 15, lhi = lane >> 4;
  __shared__ alignas(16) u16 bx[32768];      // V: Sfh|Sfl|Sbh|Sbl (4x16KB); T: xh|xl

  {
    const char* st0 = (const char*)Sf + ((size_t)(h * 8 + ct) * 2) * 16384;
    const char* st2 = (const char*)Sb + ((size_t)(h * 8 + ct) * 2) * 16384;
    const char* stile[4] = {st0, st0 + 16384, st2, st2 + 16384};
    #pragma unroll
    for (int tt = 0; tt < 4; ++tt){
      #pragma unroll
      for (int is = 0; is < 4; ++is){
        int off = is * 4096 + wv * 1024;
        GLDS16(stile[tt] + off + (lane << 4), (char*)bx + tt * 16384 + off);
      }
    }
  }
  const char* wb = (const char*)A2c + (size_t)h * 131072 + (size_t)wr * 8192 + ((u32)lane << 4);
  short8 fA[8], fB[8];
  LOAD_FRAGS(fA, wb + 4 * 16384);   // Vfh
  LOAD_FRAGS(fB, wb + 5 * 16384);   // Vfl
  asm volatile("s_waitcnt vmcnt(0)" ::: "memory");
  __syncthreads();

  f32x4 acc[4][4];
  #pragma unroll
  for (int i = 0; i < 4; ++i)
    #pragma unroll
    for (int j = 0; j < 4; ++j) acc[i][j] = (f32x4){0.f, 0.f, 0.f, 0.f};

  const char* sfh = (const char*)bx;
  const char* sfl = (const char*)bx + 16384;
  const char* sbh = (const char*)bx + 32768;
  const char* sbl = (const char*)bx + 49152;
  MFMA_PASS(fA, sfh, 0, 128);
  MFMA_PASS(fA, sfl, 0, 128);
  LOAD_FRAGS(fA, wb + 6 * 16384);   // Vbh
  MFMA_PASS(fB, sfh, 0, 128);
  LOAD_FRAGS(fB, wb + 7 * 16384);   // Vbl
  MFMA_PASS(fA, sbh, 0, 128);
  MFMA_PASS(fA, sbl, 0, 128);
  LOAD_FRAGS(fA, wb);               // Th(k0)
  MFMA_PASS(fB, sbh, 0, 128);
  LOAD_FRAGS(fB, wb + 16384);       // Th(k64)

  __syncthreads();                   // V-phase reads of S done
  stage_x_tile(X, h, ct, (char*)bx, (char*)bx + 32768, tid);
  __syncthreads();                   // x ready

  const char* xh = (const char*)bx;
  const char* xl = (const char*)bx + 32768;
  MFMA_PASS(fA, xh, 0, 256);
  MFMA_PASS(fA, xl, 0, 256);
  LOAD_FRAGS(fA, wb + 2 * 16384);   // Tl(k0)
  MFMA_PASS(fB, xh, 64, 256);
  MFMA_PASS(fB, xl, 64, 256);
  LOAD_FRAGS(fB, wb + 3 * 16384);   // Tl(k64)
  MFMA_PASS(fA, xh, 0, 256);
  MFMA_PASS(fB, xh, 64, 256);

  float Dh = Dv[h];
  #pragma unroll
  for (int mt = 0; mt < 4; ++mt)
    #pragma unroll
    for (int nt = 0; nt < 4; ++nt){
      int col = wc * 64 + nt * 16 + lan15;
      int c = ct * 8 + (col >> 4), b = col & 15;
      int i0 = wr * 64 + mt * 16 + (lhi << 2);
      u32 off = (u32)col * 256 + (u32)((2 * i0) ^ ((col & 7) << 4));
      US4 hx = *(const US4*)((const char*)bx + off);
      US4 lx = *(const US4*)((const char*)bx + 32768 + off);
      size_t base = ((size_t)b * HCH + h) * LSEQ + (size_t)c * 128 + i0;
      f32x4 ov;
      #pragma unroll
      for (int e = 0; e < 4; ++e){
        float xv = bf2f(hx.v[e]) + bf2f(lx.v[e]);
        ov[e] = geluf(acc[mt][nt][e] + Dh * xv);
      }
      *(f32x4*)&G[base] = ov;
    }
}

// ---------------- MFMA GLU+LN: reg-A, 1 barrier in GEMM; z=a*sig(g); u=z+X; LN -> X ----------------
__global__ __launch_bounds__(256) void k_glu2(
    const float* __restrict__ G,
    const u16* __restrict__ Wg,      // per-fragment layout, 4 slices x 32768 B
    const float* __restrict__ ob,
    const float* __restrict__ lng, const float* __restrict__ lnb,
    float* __restrict__ X)
{
  int b = blockIdx.y, l0 = blockIdx.x * 64;
  int tid = threadIdx.x, lane = tid & 63, wv = tid >> 6;
  int lan15 = lane & 15, lhi = lane >> 4;
  int wc = 0;                                   // cols 0..63 (single l-tile)
  __shared__ alignas(16) u16 gt[2][64 * 128];   // hi/lo : [col l][128 h], swizzled by (l&7)<<4
  __shared__ float lnbuf[4][64][2];

  {
    int hp = tid & 63, lgrp = tid >> 6;
    const float* g0 = G + ((size_t)b * HCH + 2 * hp) * LSEQ + l0 + lgrp * 16;
    const float* g1 = g0 + LSEQ;
    #pragma unroll
    for (int j4 = 0; j4 < 4; ++j4){
      f32x4 r0 = *(const f32x4*)(g0 + j4 * 4);
      f32x4 r1 = *(const f32x4*)(g1 + j4 * 4);
      #pragma unroll
      for (int e = 0; e < 4; ++e){
        int l = lgrp * 16 + j4 * 4 + e;
        u16 h0 = f2bf(r0[e]), h1 = f2bf(r1[e]);
        u16 q0 = f2bf(r0[e] - bf2f(h0)), q1 = f2bf(r1[e] - bf2f(h1));
        u32 off = (u32)l * 256 + (((u32)hp * 4) ^ (((u32)l & 7u) << 4));
        *(u32*)((char*)&gt[0][0] + off) = (u32)h0 | ((u32)h1 << 16);
        *(u32*)((char*)&gt[1][0] + off) = (u32)q0 | ((u32)q1 << 16);
      }
    }
  }
  const char* wb = (const char*)Wg + (size_t)wv * 8192 + ((u32)lane << 4);
  short8 fA[8], fB[8];
  LOAD_FRAGS(fA, wb);               // hi k0
  LOAD_FRAGS(fB, wb + 32768);       // hi k64
  __syncthreads();

  f32x4 acc[4][4];
  #pragma unroll
  for (int i = 0; i < 4; ++i)
    #pragma unroll
    for (int j = 0; j < 4; ++j) acc[i][j] = (f32x4){0.f, 0.f, 0.f, 0.f};

  const char* gh = (const char*)&gt[0][0];
  const char* gl = (const char*)&gt[1][0];
  MFMA_PASS(fA, gh, 0, 256);
  MFMA_PASS(fA, gl, 0, 256);
  LOAD_FRAGS(fA, wb + 2 * 32768);   // lo k0
  MFMA_PASS(fB, gh, 64, 256);
  MFMA_PASS(fB, gl, 64, 256);
  LOAD_FRAGS(fB, wb + 3 * 32768);   // lo k64
  MFMA_PASS(fA, gh, 0, 256);
  MFMA_PASS(fB, gh, 64, 256);

  // ---- GLU + skip; partial LN sums ----
  float s1v[4] = {0, 0, 0, 0}, s2v[4] = {0, 0, 0, 0};
  float oba[4][2], obg[4][2];
  #pragma unroll
  for (int mt = 0; mt < 4; ++mt)
    #pragma unroll
    for (int e = 0; e < 2; ++e){
      int o = wv * 32 + mt * 8 + lhi * 2 + e;
      oba[mt][e] = ob[o]; obg[mt][e] = ob[o + 128];
    }
  #pragma unroll
  for (int nt = 0; nt < 4; ++nt){
    int l = l0 + nt * 16 + lan15;
    #pragma unroll
    for (int mt = 0; mt < 4; ++mt){
      #pragma unroll
      for (int e = 0; e < 2; ++e){
        int o = wv * 32 + mt * 8 + lhi * 2 + e;
        float a = acc[mt][nt][2 * e]     + oba[mt][e];
        float g = acc[mt][nt][2 * e + 1] + obg[mt][e];
        float z = a * (1.f / (1.f + expf(-g)));
        float u = z + X[((size_t)b * HCH + o) * LSEQ + l];
        acc[mt][nt][2 * e] = u;
        s1v[nt] += u; s2v[nt] += u * u;
      }
    }
  }
  #pragma unroll
  for (int nt = 0; nt < 4; ++nt){
    s1v[nt] += __shfl_xor(s1v[nt], 16, 64);
    s1v[nt] += __shfl_xor(s1v[nt], 32, 64);
    s2v[nt] += __shfl_xor(s2v[nt], 16, 64);
    s2v[nt] += __shfl_xor(s2v[nt], 32, 64);
  }
  if (lhi == 0){
    #pragma unroll
    for (int nt = 0; nt < 4; ++nt){
      lnbuf[wv][nt * 16 + lan15][0] = s1v[nt];
      lnbuf[wv][nt * 16 + lan15][1] = s2v[nt];
    }
  }
  __syncthreads();
  #pragma unroll
  for (int nt = 0; nt < 4; ++nt){
    int col = nt * 16 + lan15;
    float S1 = lnbuf[0][col][0] + lnbuf[1][col][0] + lnbuf[2][col][0] + lnbuf[3][col][0];
    float S2 = lnbuf[0][col][1] + lnbuf[1][col][1] + lnbuf[2][col][1] + lnbuf[3][col][1];
    float mu = S1 * (1.f / 128.f);
    float var = S2 * (1.f / 128.f) - mu * mu;
    float rs = rsqrtf(var + 1e-5f);
    int l = l0 + col;
    #pragma unroll
    for (int mt = 0; mt < 4; ++mt)
      #pragma unroll
      for (int e = 0; e < 2; ++e){
        int o = wv * 32 + mt * 8 + lhi * 2 + e;
        float u = acc[mt][nt][2 * e];
        X[((size_t)b * HCH + o) * LSEQ + l] = (u - mu) * rs * lng[o] + lnb[o];
      }
  }
}

// ---------------- decoder as MFMA: M=16(5 used), K=1920, N=128 l-tile ----------------
__global__ __launch_bounds__(256, 1) void k_dec2(const u16* __restrict__ xTs, const u16* __restrict__ wd,
                                                 const float* __restrict__ bias, float* __restrict__ out){
  int b = blockIdx.y, l0 = blockIdx.x * 128;
  int tid = threadIdx.x, lane = tid & 63, wv = tid >> 6;
  int lan15 = lane & 15, lhi = lane >> 4;
  __shared__ alignas(16) u16 xt[144 * 128];
  __shared__ alignas(16) u16 ws[16 * 1920];
  const char* xsrc = (const char*)xTs + (size_t)b * XT_BSTRIDE + (size_t)l0 * 256;
  #pragma unroll
  for (int is = 0; is < 9; ++is){
    int off = is * 4096 + wv * 1024;
    GLDS16(xsrc + off + (lane << 4), (char*)xt + off);
  }
  #pragma unroll
  for (int is = 0; is < 15; ++is){
    int off = is * 4096 + wv * 1024;
    GLDS16((const char*)wd + off + (lane << 4), (char*)ws + off);
  }
  asm volatile("s_waitcnt vmcnt(0)" ::: "memory");
  __syncthreads();
  f32x4 acc[2] = {(f32x4){0, 0, 0, 0}, (f32x4){0, 0, 0, 0}};
  for (int k = 0; k < 15; ++k){
    #pragma unroll
    for (int ks = 0; ks < 4; ++ks){
      int K = k * 128 + ks * 32 + lhi * 8;
      short8 af = *(const short8*)((const char*)ws + lan15 * 3840 + (((u32)(K * 2)) ^ (((u32)lan15 & 7u) << 4)));
      #pragma unroll
      for (int nt = 0; nt < 2; ++nt){
        int ll = wv * 32 + nt * 16 + lan15;
        int lg = l0 + ll + k - 7;
        int row = ll + k + 1;
        short8 bf = *(const short8*)((const char*)xt + row * 256 + ((((ks * 32 + lhi * 8) * 2)) ^ ((lg & 7) << 4)));
        acc[nt] = __builtin_amdgcn_mfma_f32_16x16x32_bf16(af, bf, acc[nt], 0, 0, 0);
      }
    }
  }
  #pragma unroll
  for (int nt = 0; nt < 2; ++nt){
    int l = l0 + wv * 32 + nt * 16 + lan15;
    #pragma unroll
    for (int reg = 0; reg < 4; ++reg){
      int co = (lhi << 2) + reg;
      if (co < 5) out[((size_t)b * 5 + co) * LSEQ + l] = acc[nt][reg] + bias[co];
    }
  }
}

extern "C" void kernel_launch(void* const* d_in, const int* in_sizes, int n_in,
                              void* d_out, int out_size, void* d_ws, size_t ws_size,
                              hipStream_t stream){
  (void)in_sizes; (void)n_in; (void)out_size; (void)ws_size;
  const float* x_in   = (const float*)d_in[0];
  const float* enc_w  = (const float*)d_in[1];
  const float* enc_b  = (const float*)d_in[2];
  const float* rn_w1  = (const float*)d_in[3];
  const float* rn_b1  = (const float*)d_in[4];
  const float* rn_g1  = (const float*)d_in[5];
  const float* rn_be1 = (const float*)d_in[6];
  const float* rn_w2  = (const float*)d_in[7];
  const float* rn_b2  = (const float*)d_in[8];
  const float* rn_g2  = (const float*)d_in[9];
  const float* rn_be2 = (const float*)d_in[10];
  const float* lam_re = (const float*)d_in[11];
  const float* lam_im = (const float*)d_in[12];
  const float* log_dt = (const float*)d_in[13];
  const float* W_re   = (const float*)d_in[14];
  const float* W_im   = (const float*)d_in[15];
  const float* Dv     = (const float*)d_in[16];
  const float* out_w  = (const float*)d_in[17];
  const float* out_b  = (const float*)d_in[18];
  const float* ln_g   = (const float*)d_in[19];
  const float* ln_b   = (const float*)d_in[20];
  const float* dec_w  = (const float*)d_in[21];
  const float* dec_b  = (const float*)d_in[22];

  char* ws = (char*)d_ws;
  float* X    = (float*)(ws + 0ull);              // 64 MB residual stream
  float* PG   = (float*)(ws + 67108864ull);       // 64 MB: P (fp32) / G; resnet: xTsB
  u16*   xTsB = (u16*)  (ws + 67108864ull);       // 33.6 MB (resnet phase, conv1 output)
  u16*   Sf   = (u16*)  (ws + 134217728ull);      // 32 MB hi/lo swizzled fwd states
  u16*   Sb   = (u16*)  (ws + 167772160ull);      // 32 MB bwd states
  u16*   xTsA = (u16*)  (ws + 134217728ull);      // 33.6 MB (resnet + dec phases, aliases Sf/Sb)
  u16*   A1c  = (u16*)  (ws + 201326592ull);      // 8 MB
  u16*   A2c  = (u16*)  (ws + 209715200ull);      // 16 MB
  u16*   wswz = (u16*)  (ws + 226492416ull);      // 1.35 MB (frag layout)
  u16*   wdec = (u16*)  (ws + 227868672ull);      // 60 KB
  float* dssp = (float*)(ws + 227930112ull);      // 384 KB
  float* rC   = (float*)(ws + 228323328ull);      // 32 KB
  u16*   wglu = (u16*)  (ws + 228356096ull);      // 512 KB (frag layout)

  k_xpad<<<16, 256, 0, stream>>>(xTsA);
  k_xpad<<<16, 256, 0, stream>>>(xTsB);
  k_wxform<<<2688, 256, 0, stream>>>(rn_w1, rn_w2, wswz);
  k_wdec<<<120, 256, 0, stream>>>(dec_w, wdec);
  k_wglu<<<1024, 256, 0, stream>>>(out_w, wglu);
  k_dssprep<<<64, 256, 0, stream>>>(lam_re, lam_im, log_dt, W_re, W_im, dssp);
  k_enc<<<dim3(128, 16), 128, 0, stream>>>(x_in, enc_w, enc_b, X);
  k_xform<<<dim3(128, 16), 256, 0, stream>>>(X, xTsA);

  for (int r = 0; r < 3; ++r){
    k_conv<<<dim3(64, 16), 256, 0, stream>>>(xTsA, (const u16*)((char*)wswz + (size_t)(2 * r) * 229376),
        rn_g1 + r * HCH, rn_b1 + r * HCH, rn_be1 + r * HCH, nullptr, nullptr, xTsB);
    k_conv<<<dim3(64, 16), 256, 0, stream>>>(xTsB, (const u16*)((char*)wswz + (size_t)(2 * r + 1) * 229376),
        rn_g2 + r * HCH, rn_b2 + r * HCH, rn_be2 + r * HCH, X, X, (r == 2) ? nullptr : xTsA);
  }
  for (int dl = 0; dl < NLAY; ++dl){
    k_mats<<<128, 256, 0, stream>>>(dssp + (size_t)dl * 6 * HCH * NST, A1c, A2c, rC);
    k_dss1<<<dim3(128, 8), 256, 0, stream>>>(X, A1c, PG);
    k_scan<<<512, 256, 0, stream>>>(PG, rC, Sf, Sb);
    k_dss2<<<dim3(128, 8), 256, 0, stream>>>(X, A2c, Sf, Sb, Dv + dl * HCH, PG);
    k_glu2<<<dim3(128, 16), 256, 0, stream>>>(PG, (const u16*)((char*)wglu + (size_t)dl * 131072),
        out_b + dl * 256, ln_g + dl * HCH, ln_b + dl * HCH, X);
  }
  k_xpad<<<16, 256, 0, stream>>>(xTsA);
  k_xform<<<dim3(128, 16), 256, 0, stream>>>(X, xTsA);
  k_dec2<<<dim3(64, 16), 256, 0, stream>>>(xTsA, wdec, dec_b, (float*)d_out);
}